// Round 2
// baseline (4454.198 us; speedup 1.0000x reference)
//
#include <hip/hip_runtime.h>
#include <math.h>

// ---------------------------------------------------------------------------
// GATv2Conv block (N=50000, E=640000, D=128, ED=64, H=4, C=32) + LN + MLP + LN
// Outputs concatenated in d_out (ALL read back as float32 by the harness):
//   out[N*128] | ei_sl[2*(E+N)] (indices stored as float values) | alpha[(E+N)*4]
// ---------------------------------------------------------------------------

__device__ __forceinline__ float lrelu(float v) { return v > 0.f ? v : 0.2f * v; }

// ---------------- generic tiled f32 GEMM: Y[n,j] = act(sum_d X[n,d]*W[j,d] + bias[j])
// X:[nrows,K] W:[J,K] Y:[nrows,J]; K%32==0, J%64==0
template <int ACT>  // 0 = none, 1 = exact gelu
__global__ __launch_bounds__(256) void gemm_xwt(const float* __restrict__ X,
                                                const float* __restrict__ W,
                                                const float* __restrict__ bias,
                                                float* __restrict__ Y,
                                                int nrows, int K, int J) {
  __shared__ __align__(16) float Xs[32][68];
  __shared__ __align__(16) float Ws[32][68];
  const int tid = threadIdx.x;
  const int tx = tid & 15, ty = tid >> 4;
  const int n0 = blockIdx.x * 64, j0 = blockIdx.y * 64;
  const int lc = tid & 31, lr = tid >> 5;
  float acc[4][4] = {};
  for (int k0 = 0; k0 < K; k0 += 32) {
#pragma unroll
    for (int rr = 0; rr < 8; ++rr) {
      int r = lr + rr * 8;
      int n = n0 + r;
      Xs[lc][r] = (n < nrows) ? X[(size_t)n * K + k0 + lc] : 0.f;
      Ws[lc][r] = W[(size_t)(j0 + r) * K + k0 + lc];
    }
    __syncthreads();
#pragma unroll
    for (int kk = 0; kk < 32; ++kk) {
      float4 xv = *reinterpret_cast<const float4*>(&Xs[kk][ty * 4]);
      float4 wv = *reinterpret_cast<const float4*>(&Ws[kk][tx * 4]);
      float xa[4] = {xv.x, xv.y, xv.z, xv.w};
      float wa[4] = {wv.x, wv.y, wv.z, wv.w};
#pragma unroll
      for (int a = 0; a < 4; ++a)
#pragma unroll
        for (int b = 0; b < 4; ++b) acc[a][b] += xa[a] * wa[b];
    }
    __syncthreads();
  }
#pragma unroll
  for (int a = 0; a < 4; ++a) {
    int n = n0 + ty * 4 + a;
    if (n < nrows) {
      float4 st;
      float* stf = &st.x;
#pragma unroll
      for (int b = 0; b < 4; ++b) {
        int j = j0 + tx * 4 + b;
        float v = acc[a][b] + (bias ? bias[j] : 0.f);
        if (ACT == 1) v = 0.5f * v * (1.0f + erff(v * 0.70710678118654752f));
        stf[b] = v;
      }
      *reinterpret_cast<float4*>(&Y[(size_t)n * J + j0 + tx * 4]) = st;
    }
  }
}

// ---------------- in-degree counts
__global__ void deg_kernel(const int* __restrict__ ei, int* __restrict__ degc, int E) {
  int i = blockIdx.x * 256 + threadIdx.x;
  if (i < E) atomicAdd(&degc[ei[E + i]], 1);
}

// ---------------- exclusive scan (single block, 1024 threads, wave-scan based)
__global__ __launch_bounds__(1024) void scan_kernel(const int* __restrict__ deg,
                                                    int* __restrict__ row_off, int n) {
  __shared__ int wsum[16];
  __shared__ int carry_s;
  const int tid = threadIdx.x, lane = tid & 63, w = tid >> 6;
  if (tid == 0) { carry_s = 0; row_off[0] = 0; }
  __syncthreads();
  for (int base = 0; base < n; base += 1024) {
    int i = base + tid;
    int v = (i < n) ? deg[i] : 0;
    int sc = v;
#pragma unroll
    for (int o = 1; o < 64; o <<= 1) {
      int t = __shfl_up(sc, o);
      if (lane >= o) sc += t;
    }
    if (lane == 63) wsum[w] = sc;
    __syncthreads();
    int carry = carry_s;
    int woff = 0;
    for (int ww = 0; ww < w; ++ww) woff += wsum[ww];
    int incl = sc + woff + carry;
    if (i < n) row_off[i + 1] = incl;
    __syncthreads();
    if (tid == 1023) carry_s = incl;
    __syncthreads();
  }
}

// ---------------- scatter edges into CSR (grouped by dst)
__global__ void scatter_kernel(const int* __restrict__ ei, const int* __restrict__ row_off,
                               int* __restrict__ cursor, int* __restrict__ eid,
                               int* __restrict__ esrc, int E) {
  int i = blockIdx.x * 256 + threadIdx.x;
  if (i >= E) return;
  int d = ei[E + i];
  int pos = row_off[d] + atomicAdd(&cursor[d], 1);
  eid[pos] = i;
  esrc[pos] = ei[i];
}

// ---------------- per-edge logits (stored into the alpha slots of d_out)
// wave handles 4 edges at a time; We staged in LDS as float4-transposed tiles.
__global__ __launch_bounds__(256) void edge_logits_kernel(
    const float* __restrict__ edge_attr, const int* __restrict__ ei,
    const float* __restrict__ xl, const float* __restrict__ xr,
    const float* __restrict__ We, const float* __restrict__ att,
    float* __restrict__ logits4, int E) {
  __shared__ __align__(16) float WeTs[16][128][4];  // [q][j][c]: We[j*64 + 4q+c]
  for (int i = threadIdx.x; i < 128 * 64; i += 256) {
    int j = i >> 6, d = i & 63;
    WeTs[d >> 2][j][d & 3] = We[i];
  }
  __syncthreads();
  const int lane = threadIdx.x & 63;
  const float a_lo = att[lane], a_hi = att[lane + 64];
  const int wave_id = (blockIdx.x << 2) + (threadIdx.x >> 6);
  const int nwaves = gridDim.x << 2;
  const float4* wbase = reinterpret_cast<const float4*>(&WeTs[0][0][0]);
  for (int kb = wave_id * 4; kb < E; kb += nwaves * 4) {
    const int cnt = min(4, E - kb);
    float eav[4];
    int sv[4], dv[4];
#pragma unroll
    for (int e = 0; e < 4; ++e) {
      if (e < cnt) {
        eav[e] = edge_attr[(size_t)(kb + e) * 64 + lane];
        sv[e] = ei[kb + e];
        dv[e] = ei[E + kb + e];
      } else { eav[e] = 0.f; sv[e] = 0; dv[e] = 0; }
    }
    float elo[4] = {0, 0, 0, 0}, ehi[4] = {0, 0, 0, 0};
#pragma unroll
    for (int q = 0; q < 16; ++q) {
      float4 wlo = wbase[q * 128 + lane];
      float4 whi = wbase[q * 128 + lane + 64];
#pragma unroll
      for (int e = 0; e < 4; ++e) {
        float b0 = __shfl(eav[e], 4 * q + 0);
        float b1 = __shfl(eav[e], 4 * q + 1);
        float b2 = __shfl(eav[e], 4 * q + 2);
        float b3 = __shfl(eav[e], 4 * q + 3);
        elo[e] += wlo.x * b0 + wlo.y * b1 + wlo.z * b2 + wlo.w * b3;
        ehi[e] += whi.x * b0 + whi.y * b1 + whi.z * b2 + whi.w * b3;
      }
    }
#pragma unroll
    for (int e = 0; e < 4; ++e) {
      if (e >= cnt) break;
      int s = sv[e], d = dv[e];
      float g_lo = lrelu(xl[(size_t)s * 128 + lane] + xr[(size_t)d * 128 + lane] + elo[e]);
      float g_hi = lrelu(xl[(size_t)s * 128 + 64 + lane] + xr[(size_t)d * 128 + 64 + lane] + ehi[e]);
      float c_lo = a_lo * g_lo, c_hi = a_hi * g_hi;
#pragma unroll
      for (int m = 1; m < 32; m <<= 1) {
        c_lo += __shfl_xor(c_lo, m);
        c_hi += __shfl_xor(c_hi, m);
      }
      float h1 = __shfl(c_lo, 32), h3 = __shfl(c_hi, 32);
      if (lane == 0) {
        float4 lg;
        lg.x = c_lo; lg.y = h1; lg.z = c_hi; lg.w = h3;
        *reinterpret_cast<float4*>(logits4 + (size_t)(kb + e) * 4) = lg;
      }
    }
  }
}

// ---------------- per-node: loop_attr, self-loop logit, segment softmax, alpha,
// weighted sum, gat_bias, residual, LayerNorm1 -> hbuf
__global__ __launch_bounds__(256) void node_kernel(
    const float* __restrict__ x, const float* __restrict__ edge_attr,
    const float* __restrict__ xl, const float* __restrict__ xr,
    const float* __restrict__ We, const float* __restrict__ att,
    const float* __restrict__ gat_bias, const float* __restrict__ ln1g,
    const float* __restrict__ ln1b, const int* __restrict__ row_off,
    const int* __restrict__ csr_eid, const int* __restrict__ csr_src,
    float* __restrict__ alpha4, float* __restrict__ hbuf, int Nn, int E) {
  __shared__ __align__(16) float WeTs[16][128][4];
  for (int i = threadIdx.x; i < 128 * 64; i += 256) {
    int j = i >> 6, d = i & 63;
    WeTs[d >> 2][j][d & 3] = We[i];
  }
  __syncthreads();
  const int lane = threadIdx.x & 63;
  const int n = (blockIdx.x << 2) + (threadIdx.x >> 6);
  if (n >= Nn) return;
  const int rs = row_off[n], re = row_off[n + 1];
  const int deg = re - rs;

  // mean incoming edge_attr (lane = attr dim)
  float la = 0.f;
  for (int p = rs; p < re; ++p) {
    int k = csr_eid[p];
    la += edge_attr[(size_t)k * 64 + lane];
  }
  la /= fmaxf((float)deg, 1.0f);

  // self-loop e projection
  float e_lo = 0.f, e_hi = 0.f;
  const float4* wbase = reinterpret_cast<const float4*>(&WeTs[0][0][0]);
#pragma unroll
  for (int q = 0; q < 16; ++q) {
    float4 wlo = wbase[q * 128 + lane];
    float4 whi = wbase[q * 128 + lane + 64];
    float b0 = __shfl(la, 4 * q + 0);
    float b1 = __shfl(la, 4 * q + 1);
    float b2 = __shfl(la, 4 * q + 2);
    float b3 = __shfl(la, 4 * q + 3);
    e_lo += wlo.x * b0 + wlo.y * b1 + wlo.z * b2 + wlo.w * b3;
    e_hi += whi.x * b0 + whi.y * b1 + whi.z * b2 + whi.w * b3;
  }
  const float xll = xl[(size_t)n * 128 + lane];
  const float xlh = xl[(size_t)n * 128 + 64 + lane];
  float g_lo = lrelu(xll + xr[(size_t)n * 128 + lane] + e_lo);
  float g_hi = lrelu(xlh + xr[(size_t)n * 128 + 64 + lane] + e_hi);
  float c_lo = att[lane] * g_lo, c_hi = att[lane + 64] * g_hi;
#pragma unroll
  for (int m = 1; m < 32; m <<= 1) {
    c_lo += __shfl_xor(c_lo, m);
    c_hi += __shfl_xor(c_hi, m);
  }
  const float sl0 = __shfl(c_lo, 0), sl1 = __shfl(c_lo, 32);
  const float sl2 = __shfl(c_hi, 0), sl3 = __shfl(c_hi, 32);

  // segment max (self + incoming)
  float m0 = sl0, m1 = sl1, m2 = sl2, m3 = sl3;
  for (int p = rs + lane; p < re; p += 64) {
    int k = csr_eid[p];
    float4 lg = *reinterpret_cast<const float4*>(alpha4 + (size_t)k * 4);
    m0 = fmaxf(m0, lg.x); m1 = fmaxf(m1, lg.y);
    m2 = fmaxf(m2, lg.z); m3 = fmaxf(m3, lg.w);
  }
#pragma unroll
  for (int m = 1; m < 64; m <<= 1) {
    m0 = fmaxf(m0, __shfl_xor(m0, m)); m1 = fmaxf(m1, __shfl_xor(m1, m));
    m2 = fmaxf(m2, __shfl_xor(m2, m)); m3 = fmaxf(m3, __shfl_xor(m3, m));
  }

  // denominators
  float d0 = 0, d1 = 0, d2 = 0, d3 = 0;
  if (lane == 0) {
    d0 = expf(sl0 - m0); d1 = expf(sl1 - m1);
    d2 = expf(sl2 - m2); d3 = expf(sl3 - m3);
  }
  for (int p = rs + lane; p < re; p += 64) {
    int k = csr_eid[p];
    float4 lg = *reinterpret_cast<const float4*>(alpha4 + (size_t)k * 4);
    d0 += expf(lg.x - m0); d1 += expf(lg.y - m1);
    d2 += expf(lg.z - m2); d3 += expf(lg.w - m3);
  }
#pragma unroll
  for (int m = 1; m < 64; m <<= 1) {
    d0 += __shfl_xor(d0, m); d1 += __shfl_xor(d1, m);
    d2 += __shfl_xor(d2, m); d3 += __shfl_xor(d3, m);
  }
  const float i0 = 1.f / d0, i1 = 1.f / d1, i2 = 1.f / d2, i3 = 1.f / d3;

  // alpha write + weighted accumulation of xl[src]
  float out_lo = 0.f, out_hi = 0.f;
  for (int base = rs; base < re; base += 64) {
    int p = base + lane;
    float a0 = 0, a1 = 0, a2 = 0, a3 = 0;
    int sp = 0;
    if (p < re) {
      int k = csr_eid[p];
      float4 lg = *reinterpret_cast<const float4*>(alpha4 + (size_t)k * 4);
      a0 = expf(lg.x - m0) * i0; a1 = expf(lg.y - m1) * i1;
      a2 = expf(lg.z - m2) * i2; a3 = expf(lg.w - m3) * i3;
      float4 av; av.x = a0; av.y = a1; av.z = a2; av.w = a3;
      *reinterpret_cast<float4*>(alpha4 + (size_t)k * 4) = av;
      sp = csr_src[p];
    }
    int cend = min(64, re - base);
    for (int i = 0; i < cend; ++i) {
      float b0 = __shfl(a0, i), b1 = __shfl(a1, i);
      float b2 = __shfl(a2, i), b3 = __shfl(a3, i);
      int s = __shfl(sp, i);
      float w_lo = (lane < 32) ? b0 : b1;
      float w_hi = (lane < 32) ? b2 : b3;
      out_lo += w_lo * xl[(size_t)s * 128 + lane];
      out_hi += w_hi * xl[(size_t)s * 128 + 64 + lane];
    }
  }
  // self loop contribution
  const float as0 = expf(sl0 - m0) * i0, as1 = expf(sl1 - m1) * i1;
  const float as2 = expf(sl2 - m2) * i2, as3 = expf(sl3 - m3) * i3;
  out_lo += ((lane < 32) ? as0 : as1) * xll;
  out_hi += ((lane < 32) ? as2 : as3) * xlh;
  if (lane == 0) {
    float4 av; av.x = as0; av.y = as1; av.z = as2; av.w = as3;
    *reinterpret_cast<float4*>(alpha4 + (size_t)(E + n) * 4) = av;
  }

  // + gat_bias, residual, LayerNorm1
  float y_lo = x[(size_t)n * 128 + lane] + out_lo + gat_bias[lane];
  float y_hi = x[(size_t)n * 128 + 64 + lane] + out_hi + gat_bias[lane + 64];
  float tot = y_lo + y_hi;
#pragma unroll
  for (int m = 1; m < 64; m <<= 1) tot += __shfl_xor(tot, m);
  const float mu = tot * (1.0f / 128.0f);
  const float dl = y_lo - mu, dh = y_hi - mu;
  float sq = dl * dl + dh * dh;
#pragma unroll
  for (int m = 1; m < 64; m <<= 1) sq += __shfl_xor(sq, m);
  const float rstd = rsqrtf(sq * (1.0f / 128.0f) + 1e-5f);
  hbuf[(size_t)n * 128 + lane] = dl * rstd * ln1g[lane] + ln1b[lane];
  hbuf[(size_t)n * 128 + 64 + lane] = dh * rstd * ln1g[lane + 64] + ln1b[lane + 64];
}

// ---------------- LayerNorm2 over h + mlp
__global__ __launch_bounds__(256) void ln2_kernel(const float* __restrict__ hbuf,
                                                  const float* __restrict__ mlpout,
                                                  const float* __restrict__ g,
                                                  const float* __restrict__ b,
                                                  float* __restrict__ out, int Nn) {
  const int lane = threadIdx.x & 63;
  const int n = (blockIdx.x << 2) + (threadIdx.x >> 6);
  if (n >= Nn) return;
  float y_lo = hbuf[(size_t)n * 128 + lane] + mlpout[(size_t)n * 128 + lane];
  float y_hi = hbuf[(size_t)n * 128 + 64 + lane] + mlpout[(size_t)n * 128 + 64 + lane];
  float tot = y_lo + y_hi;
#pragma unroll
  for (int m = 1; m < 64; m <<= 1) tot += __shfl_xor(tot, m);
  const float mu = tot * (1.0f / 128.0f);
  const float dl = y_lo - mu, dh = y_hi - mu;
  float sq = dl * dl + dh * dh;
#pragma unroll
  for (int m = 1; m < 64; m <<= 1) sq += __shfl_xor(sq, m);
  const float rstd = rsqrtf(sq * (1.0f / 128.0f) + 1e-5f);
  out[(size_t)n * 128 + lane] = dl * rstd * g[lane] + b[lane];
  out[(size_t)n * 128 + 64 + lane] = dh * rstd * g[lane + 64] + b[lane + 64];
}

// ---------------- edge_index_sl output (written as FLOAT values: the harness
// reads the whole concatenated d_out as float32)
__global__ void ei_kernel(const int* __restrict__ ei, float* __restrict__ out_f, int E, int Nn) {
  int i = blockIdx.x * 256 + threadIdx.x;
  int Etot = E + Nn;
  if (i >= Etot) return;
  int s, d;
  if (i < E) { s = ei[i]; d = ei[E + i]; }
  else { s = i - E; d = i - E; }
  out_f[i] = (float)s;
  out_f[Etot + i] = (float)d;
}

// ---------------------------------------------------------------------------
extern "C" void kernel_launch(void* const* d_in, const int* in_sizes, int n_in,
                              void* d_out, int out_size, void* d_ws, size_t ws_size,
                              hipStream_t stream) {
  const float* x    = (const float*)d_in[0];
  const int*   ei   = (const int*)d_in[1];
  const float* ea   = (const float*)d_in[2];
  const float* Wl   = (const float*)d_in[3];
  const float* bl   = (const float*)d_in[4];
  const float* Wr   = (const float*)d_in[5];
  const float* br   = (const float*)d_in[6];
  const float* We   = (const float*)d_in[7];
  const float* att  = (const float*)d_in[8];
  const float* gb   = (const float*)d_in[9];
  const float* l1g  = (const float*)d_in[10];
  const float* l1b  = (const float*)d_in[11];
  const float* l2g  = (const float*)d_in[12];
  const float* l2b  = (const float*)d_in[13];
  const float* W1   = (const float*)d_in[14];
  const float* W2   = (const float*)d_in[15];

  const int Nn = in_sizes[0] / 128;
  const int E = in_sizes[1] / 2;
  const int Etot = E + Nn;

  // workspace layout (f32 elements)
  float* xl     = (float*)d_ws;
  float* xr     = xl + (size_t)Nn * 128;
  float* hbuf   = xr + (size_t)Nn * 128;
  float* hidden = hbuf + (size_t)Nn * 128;
  int*   deg_i  = (int*)(hidden + (size_t)Nn * 256);
  int*   cursor = deg_i + Nn;
  int*   row_off = cursor + Nn;
  int*   csr_eid = row_off + (Nn + 1);
  int*   csr_src = csr_eid + E;
  float* mlpout = xl;  // xl dead after node_kernel -> reuse

  float* outp   = (float*)d_out;
  float* ei_out = outp + (size_t)Nn * 128;
  float* alpha4 = outp + (size_t)Nn * 128 + 2 * (size_t)Etot;

  hipMemsetAsync(deg_i, 0, sizeof(int) * 2 * (size_t)Nn, stream);  // deg + cursor

  dim3 blk(256);
  dim3 gproj((Nn + 63) / 64, 2);
  gemm_xwt<0><<<gproj, blk, 0, stream>>>(x, Wl, bl, xl, Nn, 128, 128);
  gemm_xwt<0><<<gproj, blk, 0, stream>>>(x, Wr, br, xr, Nn, 128, 128);

  int eb = (E + 255) / 256;
  deg_kernel<<<eb, blk, 0, stream>>>(ei, deg_i, E);
  scan_kernel<<<1, 1024, 0, stream>>>(deg_i, row_off, Nn);
  scatter_kernel<<<eb, blk, 0, stream>>>(ei, row_off, cursor, csr_eid, csr_src, E);

  edge_logits_kernel<<<1280, blk, 0, stream>>>(ea, ei, xl, xr, We, att, alpha4, E);

  node_kernel<<<(Nn + 3) / 4, blk, 0, stream>>>(x, ea, xl, xr, We, att, gb, l1g, l1b,
                                                row_off, csr_eid, csr_src, alpha4, hbuf,
                                                Nn, E);

  dim3 gm1((Nn + 63) / 64, 4);
  gemm_xwt<1><<<gm1, blk, 0, stream>>>(hbuf, W1, nullptr, hidden, Nn, 128, 256);
  dim3 gm2((Nn + 63) / 64, 2);
  gemm_xwt<0><<<gm2, blk, 0, stream>>>(hidden, W2, nullptr, mlpout, Nn, 256, 128);

  ln2_kernel<<<(Nn + 3) / 4, blk, 0, stream>>>(hbuf, mlpout, l2g, l2b, outp, Nn);

  ei_kernel<<<(Etot + 255) / 256, blk, 0, stream>>>(ei, ei_out, E, Nn);
}

// Round 3
// 1283.589 us; speedup vs baseline: 3.4701x; 3.4701x over previous
//
#include <hip/hip_runtime.h>
#include <math.h>

// ---------------------------------------------------------------------------
// GATv2Conv block (N=50000, E=640000, D=128, ED=64, H=4, C=32) + LN + MLP + LN
// Outputs concatenated in d_out (ALL read back as float32 by the harness):
//   out[N*128] | ei_sl[2*(E+N)] (indices stored as float values) | alpha[(E+N)*4]
// ---------------------------------------------------------------------------

__device__ __forceinline__ float lrelu(float v) { return v > 0.f ? v : 0.2f * v; }

// ---------------- generic tiled f32 GEMM: Y[n,j] = act(sum_d X[n,d]*W[j,d] + bias[j])
// X:[nrows,K] W:[J,K] Y:[nrows,J]; K%32==0, J%64==0
template <int ACT>  // 0 = none, 1 = exact gelu
__global__ __launch_bounds__(256) void gemm_xwt(const float* __restrict__ X,
                                                const float* __restrict__ W,
                                                const float* __restrict__ bias,
                                                float* __restrict__ Y,
                                                int nrows, int K, int J) {
  __shared__ __align__(16) float Xs[32][68];
  __shared__ __align__(16) float Ws[32][68];
  const int tid = threadIdx.x;
  const int tx = tid & 15, ty = tid >> 4;
  const int n0 = blockIdx.x * 64, j0 = blockIdx.y * 64;
  const int lc = tid & 31, lr = tid >> 5;
  float acc[4][4] = {};
  for (int k0 = 0; k0 < K; k0 += 32) {
#pragma unroll
    for (int rr = 0; rr < 8; ++rr) {
      int r = lr + rr * 8;
      int n = n0 + r;
      Xs[lc][r] = (n < nrows) ? X[(size_t)n * K + k0 + lc] : 0.f;
      Ws[lc][r] = W[(size_t)(j0 + r) * K + k0 + lc];
    }
    __syncthreads();
#pragma unroll
    for (int kk = 0; kk < 32; ++kk) {
      float4 xv = *reinterpret_cast<const float4*>(&Xs[kk][ty * 4]);
      float4 wv = *reinterpret_cast<const float4*>(&Ws[kk][tx * 4]);
      float xa[4] = {xv.x, xv.y, xv.z, xv.w};
      float wa[4] = {wv.x, wv.y, wv.z, wv.w};
#pragma unroll
      for (int a = 0; a < 4; ++a)
#pragma unroll
        for (int b = 0; b < 4; ++b) acc[a][b] += xa[a] * wa[b];
    }
    __syncthreads();
  }
#pragma unroll
  for (int a = 0; a < 4; ++a) {
    int n = n0 + ty * 4 + a;
    if (n < nrows) {
      float4 st;
      float* stf = &st.x;
#pragma unroll
      for (int b = 0; b < 4; ++b) {
        int j = j0 + tx * 4 + b;
        float v = acc[a][b] + (bias ? bias[j] : 0.f);
        if (ACT == 1) v = 0.5f * v * (1.0f + erff(v * 0.70710678118654752f));
        stf[b] = v;
      }
      *reinterpret_cast<float4*>(&Y[(size_t)n * J + j0 + tx * 4]) = st;
    }
  }
}

// ---------------- in-degree counts
__global__ void deg_kernel(const int* __restrict__ ei, int* __restrict__ degc, int E) {
  int i = blockIdx.x * 256 + threadIdx.x;
  if (i < E) atomicAdd(&degc[ei[E + i]], 1);
}

// ---------------- exclusive scan (single block, 1024 threads, wave-scan based)
__global__ __launch_bounds__(1024) void scan_kernel(const int* __restrict__ deg,
                                                    int* __restrict__ row_off, int n) {
  __shared__ int wsum[16];
  __shared__ int carry_s;
  const int tid = threadIdx.x, lane = tid & 63, w = tid >> 6;
  if (tid == 0) { carry_s = 0; row_off[0] = 0; }
  __syncthreads();
  for (int base = 0; base < n; base += 1024) {
    int i = base + tid;
    int v = (i < n) ? deg[i] : 0;
    int sc = v;
#pragma unroll
    for (int o = 1; o < 64; o <<= 1) {
      int t = __shfl_up(sc, o);
      if (lane >= o) sc += t;
    }
    if (lane == 63) wsum[w] = sc;
    __syncthreads();
    int carry = carry_s;
    int woff = 0;
    for (int ww = 0; ww < w; ++ww) woff += wsum[ww];
    int incl = sc + woff + carry;
    if (i < n) row_off[i + 1] = incl;
    __syncthreads();
    if (tid == 1023) carry_s = incl;
    __syncthreads();
  }
}

// ---------------- scatter edges into CSR (grouped by dst)
__global__ void scatter_kernel(const int* __restrict__ ei, const int* __restrict__ row_off,
                               int* __restrict__ cursor, int* __restrict__ eid,
                               int* __restrict__ esrc, int E) {
  int i = blockIdx.x * 256 + threadIdx.x;
  if (i >= E) return;
  int d = ei[E + i];
  int pos = row_off[d] + atomicAdd(&cursor[d], 1);
  eid[pos] = i;
  esrc[pos] = ei[i];
}

// ---------------- edge combine: logits[e,h] = sum_c att[h,c]*lrelu(xl[s]+xr[d]+eproj[e])
// lane -> dims (2*lane, 2*lane+1); heads are 16-lane groups; 8 edges in flight.
__global__ __launch_bounds__(256) void edge_combine_kernel(
    const float* __restrict__ eproj, const int* __restrict__ ei,
    const float* __restrict__ xl, const float* __restrict__ xr,
    const float* __restrict__ att, float* __restrict__ logits4,
    int e0, int e1, int E) {
  const int lane = threadIdx.x & 63;
  const float2 a2 = reinterpret_cast<const float2*>(att)[lane];
  const int wave = blockIdx.x * 4 + (threadIdx.x >> 6);
  const int nw = gridDim.x * 4;
  constexpr int EG = 8;
  for (int kb = e0 + wave * EG; kb < e1; kb += nw * EG) {
    const int cnt = min(EG, e1 - kb);
    float2 ep[EG], xlv[EG], xrv[EG];
#pragma unroll
    for (int e = 0; e < EG; ++e) {
      int idx = kb + ((e < cnt) ? e : 0);
      int s = ei[idx];
      int d = ei[E + idx];
      ep[e]  = reinterpret_cast<const float2*>(eproj + (size_t)(idx - e0) * 128)[lane];
      xlv[e] = reinterpret_cast<const float2*>(xl + (size_t)s * 128)[lane];
      xrv[e] = reinterpret_cast<const float2*>(xr + (size_t)d * 128)[lane];
    }
#pragma unroll
    for (int e = 0; e < EG; ++e) {
      if (e >= cnt) break;
      float g0 = lrelu(xlv[e].x + xrv[e].x + ep[e].x);
      float g1 = lrelu(xlv[e].y + xrv[e].y + ep[e].y);
      float c = a2.x * g0 + a2.y * g1;
      c += __shfl_xor(c, 1);
      c += __shfl_xor(c, 2);
      c += __shfl_xor(c, 4);
      c += __shfl_xor(c, 8);
      float h1 = __shfl(c, 16), h2 = __shfl(c, 32), h3 = __shfl(c, 48);
      if (lane == 0) {
        float4 lg;
        lg.x = c; lg.y = h1; lg.z = h2; lg.w = h3;
        *reinterpret_cast<float4*>(logits4 + (size_t)(kb + e) * 4) = lg;
      }
    }
  }
}

// ---------------- per-node: loop_attr, self-loop logit, segment softmax, alpha,
// weighted sum, gat_bias, residual, LayerNorm1 -> hbuf
__global__ __launch_bounds__(256) void node_kernel(
    const float* __restrict__ x, const float* __restrict__ edge_attr,
    const float* __restrict__ xl, const float* __restrict__ xr,
    const float* __restrict__ We, const float* __restrict__ att,
    const float* __restrict__ gat_bias, const float* __restrict__ ln1g,
    const float* __restrict__ ln1b, const int* __restrict__ row_off,
    const int* __restrict__ csr_eid, const int* __restrict__ csr_src,
    float* __restrict__ alpha4, float* __restrict__ hbuf, int Nn, int E) {
  __shared__ __align__(16) float WeTs[16][128][4];
  for (int i = threadIdx.x; i < 128 * 64; i += 256) {
    int j = i >> 6, d = i & 63;
    WeTs[d >> 2][j][d & 3] = We[i];
  }
  __syncthreads();
  const int lane = threadIdx.x & 63;
  const int n = (blockIdx.x << 2) + (threadIdx.x >> 6);
  if (n >= Nn) return;
  const int rs = row_off[n], re = row_off[n + 1];
  const int deg = re - rs;

  // mean incoming edge_attr (lane = attr dim)
  float la = 0.f;
  for (int p = rs; p < re; ++p) {
    int k = csr_eid[p];
    la += edge_attr[(size_t)k * 64 + lane];
  }
  la /= fmaxf((float)deg, 1.0f);

  // self-loop e projection
  float e_lo = 0.f, e_hi = 0.f;
  const float4* wbase = reinterpret_cast<const float4*>(&WeTs[0][0][0]);
#pragma unroll
  for (int q = 0; q < 16; ++q) {
    float4 wlo = wbase[q * 128 + lane];
    float4 whi = wbase[q * 128 + lane + 64];
    float b0 = __shfl(la, 4 * q + 0);
    float b1 = __shfl(la, 4 * q + 1);
    float b2 = __shfl(la, 4 * q + 2);
    float b3 = __shfl(la, 4 * q + 3);
    e_lo += wlo.x * b0 + wlo.y * b1 + wlo.z * b2 + wlo.w * b3;
    e_hi += whi.x * b0 + whi.y * b1 + whi.z * b2 + whi.w * b3;
  }
  const float xll = xl[(size_t)n * 128 + lane];
  const float xlh = xl[(size_t)n * 128 + 64 + lane];
  float g_lo = lrelu(xll + xr[(size_t)n * 128 + lane] + e_lo);
  float g_hi = lrelu(xlh + xr[(size_t)n * 128 + 64 + lane] + e_hi);
  float c_lo = att[lane] * g_lo, c_hi = att[lane + 64] * g_hi;
#pragma unroll
  for (int m = 1; m < 32; m <<= 1) {
    c_lo += __shfl_xor(c_lo, m);
    c_hi += __shfl_xor(c_hi, m);
  }
  const float sl0 = __shfl(c_lo, 0), sl1 = __shfl(c_lo, 32);
  const float sl2 = __shfl(c_hi, 0), sl3 = __shfl(c_hi, 32);

  // segment max (self + incoming)
  float m0 = sl0, m1 = sl1, m2 = sl2, m3 = sl3;
  for (int p = rs + lane; p < re; p += 64) {
    int k = csr_eid[p];
    float4 lg = *reinterpret_cast<const float4*>(alpha4 + (size_t)k * 4);
    m0 = fmaxf(m0, lg.x); m1 = fmaxf(m1, lg.y);
    m2 = fmaxf(m2, lg.z); m3 = fmaxf(m3, lg.w);
  }
#pragma unroll
  for (int m = 1; m < 64; m <<= 1) {
    m0 = fmaxf(m0, __shfl_xor(m0, m)); m1 = fmaxf(m1, __shfl_xor(m1, m));
    m2 = fmaxf(m2, __shfl_xor(m2, m)); m3 = fmaxf(m3, __shfl_xor(m3, m));
  }

  // denominators
  float d0 = 0, d1 = 0, d2 = 0, d3 = 0;
  if (lane == 0) {
    d0 = expf(sl0 - m0); d1 = expf(sl1 - m1);
    d2 = expf(sl2 - m2); d3 = expf(sl3 - m3);
  }
  for (int p = rs + lane; p < re; p += 64) {
    int k = csr_eid[p];
    float4 lg = *reinterpret_cast<const float4*>(alpha4 + (size_t)k * 4);
    d0 += expf(lg.x - m0); d1 += expf(lg.y - m1);
    d2 += expf(lg.z - m2); d3 += expf(lg.w - m3);
  }
#pragma unroll
  for (int m = 1; m < 64; m <<= 1) {
    d0 += __shfl_xor(d0, m); d1 += __shfl_xor(d1, m);
    d2 += __shfl_xor(d2, m); d3 += __shfl_xor(d3, m);
  }
  const float i0 = 1.f / d0, i1 = 1.f / d1, i2 = 1.f / d2, i3 = 1.f / d3;

  // alpha write + weighted accumulation of xl[src]
  float out_lo = 0.f, out_hi = 0.f;
  for (int base = rs; base < re; base += 64) {
    int p = base + lane;
    float a0 = 0, a1 = 0, a2 = 0, a3 = 0;
    int sp = 0;
    if (p < re) {
      int k = csr_eid[p];
      float4 lg = *reinterpret_cast<const float4*>(alpha4 + (size_t)k * 4);
      a0 = expf(lg.x - m0) * i0; a1 = expf(lg.y - m1) * i1;
      a2 = expf(lg.z - m2) * i2; a3 = expf(lg.w - m3) * i3;
      float4 av; av.x = a0; av.y = a1; av.z = a2; av.w = a3;
      *reinterpret_cast<float4*>(alpha4 + (size_t)k * 4) = av;
      sp = csr_src[p];
    }
    int cend = min(64, re - base);
    for (int i = 0; i < cend; ++i) {
      float b0 = __shfl(a0, i), b1 = __shfl(a1, i);
      float b2 = __shfl(a2, i), b3 = __shfl(a3, i);
      int s = __shfl(sp, i);
      float w_lo = (lane < 32) ? b0 : b1;
      float w_hi = (lane < 32) ? b2 : b3;
      out_lo += w_lo * xl[(size_t)s * 128 + lane];
      out_hi += w_hi * xl[(size_t)s * 128 + 64 + lane];
    }
  }
  // self loop contribution
  const float as0 = expf(sl0 - m0) * i0, as1 = expf(sl1 - m1) * i1;
  const float as2 = expf(sl2 - m2) * i2, as3 = expf(sl3 - m3) * i3;
  out_lo += ((lane < 32) ? as0 : as1) * xll;
  out_hi += ((lane < 32) ? as2 : as3) * xlh;
  if (lane == 0) {
    float4 av; av.x = as0; av.y = as1; av.z = as2; av.w = as3;
    *reinterpret_cast<float4*>(alpha4 + (size_t)(E + n) * 4) = av;
  }

  // + gat_bias, residual, LayerNorm1
  float y_lo = x[(size_t)n * 128 + lane] + out_lo + gat_bias[lane];
  float y_hi = x[(size_t)n * 128 + 64 + lane] + out_hi + gat_bias[lane + 64];
  float tot = y_lo + y_hi;
#pragma unroll
  for (int m = 1; m < 64; m <<= 1) tot += __shfl_xor(tot, m);
  const float mu = tot * (1.0f / 128.0f);
  const float dl = y_lo - mu, dh = y_hi - mu;
  float sq = dl * dl + dh * dh;
#pragma unroll
  for (int m = 1; m < 64; m <<= 1) sq += __shfl_xor(sq, m);
  const float rstd = rsqrtf(sq * (1.0f / 128.0f) + 1e-5f);
  hbuf[(size_t)n * 128 + lane] = dl * rstd * ln1g[lane] + ln1b[lane];
  hbuf[(size_t)n * 128 + 64 + lane] = dh * rstd * ln1g[lane + 64] + ln1b[lane + 64];
}

// ---------------- LayerNorm2 over h + mlp
__global__ __launch_bounds__(256) void ln2_kernel(const float* __restrict__ hbuf,
                                                  const float* __restrict__ mlpout,
                                                  const float* __restrict__ g,
                                                  const float* __restrict__ b,
                                                  float* __restrict__ out, int Nn) {
  const int lane = threadIdx.x & 63;
  const int n = (blockIdx.x << 2) + (threadIdx.x >> 6);
  if (n >= Nn) return;
  float y_lo = hbuf[(size_t)n * 128 + lane] + mlpout[(size_t)n * 128 + lane];
  float y_hi = hbuf[(size_t)n * 128 + 64 + lane] + mlpout[(size_t)n * 128 + 64 + lane];
  float tot = y_lo + y_hi;
#pragma unroll
  for (int m = 1; m < 64; m <<= 1) tot += __shfl_xor(tot, m);
  const float mu = tot * (1.0f / 128.0f);
  const float dl = y_lo - mu, dh = y_hi - mu;
  float sq = dl * dl + dh * dh;
#pragma unroll
  for (int m = 1; m < 64; m <<= 1) sq += __shfl_xor(sq, m);
  const float rstd = rsqrtf(sq * (1.0f / 128.0f) + 1e-5f);
  out[(size_t)n * 128 + lane] = dl * rstd * g[lane] + b[lane];
  out[(size_t)n * 128 + 64 + lane] = dh * rstd * g[lane + 64] + b[lane + 64];
}

// ---------------- edge_index_sl output (as FLOAT values; harness reads d_out as f32)
__global__ void ei_kernel(const int* __restrict__ ei, float* __restrict__ out_f, int E, int Nn) {
  int i = blockIdx.x * 256 + threadIdx.x;
  int Etot = E + Nn;
  if (i >= Etot) return;
  int s, d;
  if (i < E) { s = ei[i]; d = ei[E + i]; }
  else { s = i - E; d = i - E; }
  out_f[i] = (float)s;
  out_f[Etot + i] = (float)d;
}

// ---------------------------------------------------------------------------
extern "C" void kernel_launch(void* const* d_in, const int* in_sizes, int n_in,
                              void* d_out, int out_size, void* d_ws, size_t ws_size,
                              hipStream_t stream) {
  const float* x    = (const float*)d_in[0];
  const int*   ei   = (const int*)d_in[1];
  const float* ea   = (const float*)d_in[2];
  const float* Wl   = (const float*)d_in[3];
  const float* bl   = (const float*)d_in[4];
  const float* Wr   = (const float*)d_in[5];
  const float* br   = (const float*)d_in[6];
  const float* We   = (const float*)d_in[7];
  const float* att  = (const float*)d_in[8];
  const float* gb   = (const float*)d_in[9];
  const float* l1g  = (const float*)d_in[10];
  const float* l1b  = (const float*)d_in[11];
  const float* l2g  = (const float*)d_in[12];
  const float* l2b  = (const float*)d_in[13];
  const float* W1   = (const float*)d_in[14];
  const float* W2   = (const float*)d_in[15];

  const int Nn = in_sizes[0] / 128;
  const int E = in_sizes[1] / 2;
  const int Etot = E + Nn;

  // workspace layout (f32 elements)
  float* xl     = (float*)d_ws;
  float* xr     = xl + (size_t)Nn * 128;
  float* hbuf   = xr + (size_t)Nn * 128;
  int*   deg_i  = (int*)(hbuf + (size_t)Nn * 128);
  int*   cursor = deg_i + Nn;
  int*   row_off = cursor + Nn;
  int*   csr_eid = row_off + (Nn + 1);
  int*   csr_src = csr_eid + E;
  // big shared tail: eproj chunks (edge phase), then hidden (MLP phase)
  uintptr_t tail = (uintptr_t)(csr_src + E);
  tail = (tail + 255) & ~(uintptr_t)255;
  float* bigbuf = (float*)tail;
  size_t avail = ws_size - (size_t)(tail - (uintptr_t)d_ws);
  float* mlpout = xl;  // xl dead after node_kernel -> reuse
  float* hidden = bigbuf;

  // eproj chunk size: 128 f32 per edge = 512 B
  int chunkE = (int)((avail / 512 < (size_t)E) ? (avail / 512) : (size_t)E);

  float* outp   = (float*)d_out;
  float* ei_out = outp + (size_t)Nn * 128;
  float* alpha4 = outp + (size_t)Nn * 128 + 2 * (size_t)Etot;

  hipMemsetAsync(deg_i, 0, sizeof(int) * 2 * (size_t)Nn, stream);  // deg + cursor

  dim3 blk(256);
  dim3 gproj((Nn + 63) / 64, 2);
  gemm_xwt<0><<<gproj, blk, 0, stream>>>(x, Wl, bl, xl, Nn, 128, 128);
  gemm_xwt<0><<<gproj, blk, 0, stream>>>(x, Wr, br, xr, Nn, 128, 128);

  int eb = (E + 255) / 256;
  deg_kernel<<<eb, blk, 0, stream>>>(ei, deg_i, E);
  scan_kernel<<<1, 1024, 0, stream>>>(deg_i, row_off, Nn);
  scatter_kernel<<<eb, blk, 0, stream>>>(ei, row_off, cursor, csr_eid, csr_src, E);

  // edge logits: GEMM (eproj) + combine, chunked through the workspace tail
  for (int c0 = 0; c0 < E; c0 += chunkE) {
    int cnt = (E - c0 < chunkE) ? (E - c0) : chunkE;
    dim3 ge((cnt + 63) / 64, 2);
    gemm_xwt<0><<<ge, blk, 0, stream>>>(ea + (size_t)c0 * 64, We, nullptr, bigbuf, cnt, 64, 128);
    int cb = (cnt + 31) / 32;
    if (cb > 2048) cb = 2048;
    edge_combine_kernel<<<cb, blk, 0, stream>>>(bigbuf, ei, xl, xr, att, alpha4,
                                                c0, c0 + cnt, E);
  }

  node_kernel<<<(Nn + 3) / 4, blk, 0, stream>>>(x, ea, xl, xr, We, att, gb, l1g, l1b,
                                                row_off, csr_eid, csr_src, alpha4, hbuf,
                                                Nn, E);

  dim3 gm1((Nn + 63) / 64, 4);
  gemm_xwt<1><<<gm1, blk, 0, stream>>>(hbuf, W1, nullptr, hidden, Nn, 128, 256);
  dim3 gm2((Nn + 63) / 64, 2);
  gemm_xwt<0><<<gm2, blk, 0, stream>>>(hidden, W2, nullptr, mlpout, Nn, 256, 128);

  ln2_kernel<<<(Nn + 3) / 4, blk, 0, stream>>>(hbuf, mlpout, l2g, l2b, outp, Nn);

  ei_kernel<<<(Etot + 255) / 256, blk, 0, stream>>>(ei, ei_out, E, Nn);
}